// Round 1
// baseline (1586.921 us; speedup 1.0000x reference)
//
#include <hip/hip_runtime.h>
#include <math.h>

#define BTOT 262144
#define FDIM 256
#define KK 20
#define HH 64
#define MM 32

#define IMP_OFF  (BTOT * KK)            // 5242880
#define CWM_OFF  (IMP_OFF + KK)         // 5242900
#define ACT_OFF  (CWM_OFF + KK)         // 5242920
#define PAIR_OFF (ACT_OFF + 1)          // 5242921

__device__ __forceinline__ bool better(float v2, int p2, float v1, int p1) {
  return (v2 > v1) || (v2 == v1 && p2 < p1);
}

// ---------------- Top-K stage 1: per-row top-20 ----------------
__global__ void topk_stage1(const float* __restrict__ w,
                            float* __restrict__ cand_v, int* __restrict__ cand_p) {
  const int i = blockIdx.x;
  const int j = threadIdx.x;
  const int lane = j & 63, wid = j >> 6;
  __shared__ float sv[256];
  __shared__ float rv[4];
  __shared__ int rp[4];

  sv[j] = (j > i) ? w[i * 256 + j] : -1e30f;
  __syncthreads();

  for (int r = 0; r < 20; ++r) {
    float v = sv[j];
    int p = i * 256 + j;
    #pragma unroll
    for (int off = 32; off; off >>= 1) {
      float v2 = __shfl_down(v, off);
      int p2 = __shfl_down(p, off);
      if (better(v2, p2, v, p)) { v = v2; p = p2; }
    }
    if (lane == 0) { rv[wid] = v; rp[wid] = p; }
    __syncthreads();
    if (j == 0) {
      #pragma unroll
      for (int t = 1; t < 4; ++t)
        if (better(rv[t], rp[t], v, p)) { v = rv[t]; p = rp[t]; }
      cand_v[i * 20 + r] = v;
      cand_p[i * 20 + r] = p;
      sv[p & 255] = -2e30f;
    }
    __syncthreads();
  }
}

// ---------------- Top-K stage 2: merge 256*20 candidates ----------------
#define NC 5120
__global__ void topk_stage2(const float* __restrict__ cand_v, const int* __restrict__ cand_p,
                            int* __restrict__ pij, float* __restrict__ out) {
  const int tid = threadIdx.x;
  const int lane = tid & 63, wid = tid >> 6;
  __shared__ float sv[NC];
  __shared__ int sp[NC];
  __shared__ float rv[4];
  __shared__ int rp[4], rq[4];
  __shared__ float selv[20];
  __shared__ int selp[20];

  for (int t = tid; t < NC; t += 256) { sv[t] = cand_v[t]; sp[t] = cand_p[t]; }
  __syncthreads();

  for (int r = 0; r < 20; ++r) {
    float v = -4e30f;
    int p = 0x7fffffff, q = 0;
    for (int t = tid; t < NC; t += 256) {
      float vv = sv[t];
      int pp = sp[t];
      if (better(vv, pp, v, p)) { v = vv; p = pp; q = t; }
    }
    #pragma unroll
    for (int off = 32; off; off >>= 1) {
      float v2 = __shfl_down(v, off);
      int p2 = __shfl_down(p, off);
      int q2 = __shfl_down(q, off);
      if (better(v2, p2, v, p)) { v = v2; p = p2; q = q2; }
    }
    if (lane == 0) { rv[wid] = v; rp[wid] = p; rq[wid] = q; }
    __syncthreads();
    if (tid == 0) {
      #pragma unroll
      for (int t = 1; t < 4; ++t)
        if (better(rv[t], rp[t], v, p)) { v = rv[t]; p = rp[t]; q = rq[t]; }
      selv[r] = v;
      selp[r] = p;
      sv[q] = -3e30f;
    }
    __syncthreads();
  }

  if (tid == 0) {
    int active = 0;
    for (int r = 0; r < 20; ++r) {
      int p = selp[r];
      int i = p >> 8, j = p & 255;
      float s = 1.0f / (1.0f + expf(-selv[r]));
      out[IMP_OFF + r] = s;
      out[PAIR_OFF + 2 * r] = (float)i;
      out[PAIR_OFF + 2 * r + 1] = (float)j;
      if (s > 0.1f) active++;
      pij[r] = i;
      pij[20 + r] = j;
    }
    out[ACT_OFF] = (float)active;
  }
}

// ---------------- Main kernel ----------------
// 256 threads = 256 samples/block. x staged through LDS in 32-feature chunks.
// KEY CHANGE vs previous version: every per-thread register array (h[64],
// pv[40], ctx[20]) is now accessed ONLY with compile-time indices, so nothing
// is demoted to scratch (previous version: 724 MB of HBM spill writes,
// VGPR_Count=64). Runtime-k accesses go through LDS or an unrolled
// uniform-compare select chain instead.
#define FCH 32
#define NCHUNK (FDIM / FCH)   // 8
#define XSTR 33               // LDS row stride (floats)

__global__ __launch_bounds__(256, 3) void id_main(
    const float* __restrict__ x,
    const float* __restrict__ Wc1, const float* __restrict__ bc1,
    const float* __restrict__ Wc2, const float* __restrict__ bc2,
    const float* __restrict__ W1, const float* __restrict__ b1,
    const float* __restrict__ W2, const float* __restrict__ b2,
    const float* __restrict__ W3, const float* __restrict__ b3,
    const int* __restrict__ pij,
    float* __restrict__ ctx_sums,
    float* __restrict__ out) {
  __shared__ __align__(16) float xs[256 * XSTR];   // 33792 B; reused as out-stage
  __shared__ float csum[KK];

  const int tid = threadIdx.x;
  const int b0 = blockIdx.x * 256;
  if (tid < KK) csum[tid] = 0.0f;

  // pair columns: force into SGPRs (uniform across the grid)
  int pcol[2 * KK];
  #pragma unroll
  for (int i = 0; i < 2 * KK; ++i) pcol[i] = __builtin_amdgcn_readfirstlane(pij[i]);

  float h[HH];
  #pragma unroll
  for (int j = 0; j < HH; ++j) h[j] = bc1[j];
  float pv[2 * KK];
  #pragma unroll
  for (int i = 0; i < 2 * KK; ++i) pv[i] = 0.0f;

  const int srow = tid >> 3;       // 0..31
  const int quad = tid & 7;        // 0..7
  const float* __restrict__ xrow_lds = &xs[tid * XSTR];

  #pragma unroll 1
  for (int c = 0; c < NCHUNK; ++c) {
    const int f0 = c * FCH;
    __syncthreads();   // previous chunk's readers done before overwrite
    // ---- stage chunk: 256 rows x 32 feats, coalesced float4 ----
    const float* __restrict__ xg = x + (size_t)(b0 + srow) * FDIM + f0 + quad * 4;
    #pragma unroll
    for (int r = 0; r < 8; ++r) {
      const float4 v = *(const float4*)(xg + (size_t)r * 32 * FDIM);
      float* d = &xs[(srow + r * 32) * XSTR + quad * 4];
      d[0] = v.x; d[1] = v.y; d[2] = v.z; d[3] = v.w;
    }
    __syncthreads();
    // ---- ctx hidden accumulation over this chunk (h[j] index always static) ----
    #pragma unroll 2
    for (int f = 0; f < FCH; ++f) {
      const float xv = xrow_lds[f];
      const float* __restrict__ w0 = Wc1 + (size_t)(f0 + f) * HH;
      #pragma unroll
      for (int j = 0; j < HH; ++j) h[j] = fmaf(xv, w0[j], h[j]);
    }
    // ---- pair-column extraction (scalar compare/branch; pv index static) ----
    #pragma unroll
    for (int i = 0; i < 2 * KK; ++i) {
      const int cc = pcol[i];
      if (cc >= f0 && cc < f0 + FCH) pv[i] = xrow_lds[cc - f0];
    }
  }

  // ---- ctx output layer: FULLY unrolled so h[j] stays a static index ----
  float ctx[KK];
  #pragma unroll
  for (int k = 0; k < KK; ++k) ctx[k] = bc2[k];
  #pragma unroll
  for (int j = 0; j < HH; ++j) {
    const float hj = fmaxf(h[j], 0.0f);
    const float* __restrict__ wr = Wc2 + j * KK;
    #pragma unroll
    for (int k = 0; k < KK; ++k) ctx[k] = fmaf(hj, wr[k], ctx[k]);
  }
  #pragma unroll
  for (int k = 0; k < KK; ++k) ctx[k] = 1.0f / (1.0f + expf(-ctx[k]));

  __syncthreads();   // all xs readers done; reuse xs as out-stage
  float* __restrict__ so = xs;

  // ---- 20 pair MLPs; pa/pb via uniform-k select chain (pv stays in VGPRs) ----
  #pragma unroll 1
  for (int k = 0; k < KK; ++k) {
    float pa = 0.0f, pb = 0.0f;
    #pragma unroll
    for (int i = 0; i < KK; ++i)
      if (k == i) { pa = pv[i]; pb = pv[KK + i]; }

    const float* __restrict__ w1k = W1 + (size_t)k * 2 * HH;
    const float* __restrict__ b1k = b1 + (size_t)k * HH;
    const float* __restrict__ w2k = W2 + (size_t)k * HH * MM;
    const float* __restrict__ b2k = b2 + (size_t)k * MM;

    float h2[MM];
    #pragma unroll
    for (int m = 0; m < MM; ++m) h2[m] = b2k[m];

    // h1 computed on the fly (no h1 array); h2[m] index always static
    #pragma unroll 2
    for (int j = 0; j < HH; ++j) {
      const float h1j = fmaxf(fmaf(pa, w1k[j], fmaf(pb, w1k[HH + j], b1k[j])), 0.0f);
      const float* __restrict__ wr = w2k + j * MM;
      #pragma unroll
      for (int m = 0; m < MM; ++m) h2[m] = fmaf(h1j, wr[m], h2[m]);
    }

    const float* __restrict__ w3k = W3 + (size_t)k * MM;
    float o = b3[k];
    #pragma unroll
    for (int m = 0; m < MM; ++m) o = fmaf(fmaxf(h2[m], 0.0f), w3k[m], o);

    so[tid * KK + k] = o;   // raw o; ctx applied below with static index
  }

  // ---- apply ctx with static k (so is LDS, runtime index fine there) ----
  #pragma unroll
  for (int k = 0; k < KK; ++k) so[tid * KK + k] *= ctx[k];

  // ---- ctx mean: fully unrolled (ctx[k] static) wave shuffle -> LDS -> global ----
  const int lane = tid & 63;
  #pragma unroll
  for (int k = 0; k < KK; ++k) {
    float v = ctx[k];
    #pragma unroll
    for (int off = 32; off; off >>= 1) v += __shfl_down(v, off);
    if (lane == 0) atomicAdd(&csum[k], v);
  }
  __syncthreads();   // so[] fully written + csum done
  if (tid < KK) atomicAdd(&ctx_sums[tid], csum[tid]);

  // ---- coalesced write-out: 256*20 floats = 1280 float4 ----
  const float4* __restrict__ sof = (const float4*)so;
  float4* __restrict__ og = (float4*)(out + (size_t)b0 * KK);
  #pragma unroll
  for (int i = 0; i < 5; ++i) og[tid + i * 256] = sof[tid + i * 256];
}

__global__ void id_finalize(const float* __restrict__ ctx_sums, float* __restrict__ out) {
  const int k = threadIdx.x;
  if (k < KK) out[CWM_OFF + k] = ctx_sums[k] * (1.0f / (float)BTOT);
}

extern "C" void kernel_launch(void* const* d_in, const int* in_sizes, int n_in,
                              void* d_out, int out_size, void* d_ws, size_t ws_size,
                              hipStream_t stream) {
  const float* x   = (const float*)d_in[0];
  const float* iw  = (const float*)d_in[1];
  const float* Wc1 = (const float*)d_in[2];
  const float* bc1 = (const float*)d_in[3];
  const float* Wc2 = (const float*)d_in[4];
  const float* bc2 = (const float*)d_in[5];
  const float* W1  = (const float*)d_in[6];
  const float* b1  = (const float*)d_in[7];
  const float* W2  = (const float*)d_in[8];
  const float* b2  = (const float*)d_in[9];
  const float* W3  = (const float*)d_in[10];
  const float* b3  = (const float*)d_in[11];
  float* out = (float*)d_out;

  float* wsf    = (float*)d_ws;
  float* cand_v = wsf;                  // 5120 floats
  int*   cand_p = (int*)(wsf + 5120);   // 5120 ints
  int*   pij    = (int*)(wsf + 10240);  // 40 ints
  float* csums  = wsf + 10280;          // 20 floats

  hipMemsetAsync(csums, 0, KK * sizeof(float), stream);
  topk_stage1<<<256, 256, 0, stream>>>(iw, cand_v, cand_p);
  topk_stage2<<<1, 256, 0, stream>>>(cand_v, cand_p, pij, out);
  id_main<<<BTOT / 256, 256, 0, stream>>>(x, Wc1, bc1, Wc2, bc2, W1, b1, W2, b2, W3, b3,
                                          pij, csums, out);
  id_finalize<<<1, 64, 0, stream>>>(csums, out);
}

// Round 2
// 1021.871 us; speedup vs baseline: 1.5530x; 1.5530x over previous
//
#include <hip/hip_runtime.h>
#include <math.h>

#define BTOT 262144
#define FDIM 256
#define KK 20
#define HH 64
#define MM 32

#define IMP_OFF  (BTOT * KK)            // 5242880
#define CWM_OFF  (IMP_OFF + KK)         // 5242900
#define ACT_OFF  (CWM_OFF + KK)         // 5242920
#define PAIR_OFF (ACT_OFF + 1)          // 5242921

__device__ __forceinline__ bool better(float v2, int p2, float v1, int p1) {
  return (v2 > v1) || (v2 == v1 && p2 < p1);
}

// ---------------- Top-K stage 1: per-row top-20 ----------------
__global__ void topk_stage1(const float* __restrict__ w,
                            float* __restrict__ cand_v, int* __restrict__ cand_p) {
  const int i = blockIdx.x;
  const int j = threadIdx.x;
  const int lane = j & 63, wid = j >> 6;
  __shared__ float sv[256];
  __shared__ float rv[4];
  __shared__ int rp[4];

  sv[j] = (j > i) ? w[i * 256 + j] : -1e30f;
  __syncthreads();

  for (int r = 0; r < 20; ++r) {
    float v = sv[j];
    int p = i * 256 + j;
    #pragma unroll
    for (int off = 32; off; off >>= 1) {
      float v2 = __shfl_down(v, off);
      int p2 = __shfl_down(p, off);
      if (better(v2, p2, v, p)) { v = v2; p = p2; }
    }
    if (lane == 0) { rv[wid] = v; rp[wid] = p; }
    __syncthreads();
    if (j == 0) {
      #pragma unroll
      for (int t = 1; t < 4; ++t)
        if (better(rv[t], rp[t], v, p)) { v = rv[t]; p = rp[t]; }
      cand_v[i * 20 + r] = v;
      cand_p[i * 20 + r] = p;
      sv[p & 255] = -2e30f;
    }
    __syncthreads();
  }
}

// ---------------- Top-K stage 2: merge 256*20 candidates ----------------
#define NC 5120
__global__ void topk_stage2(const float* __restrict__ cand_v, const int* __restrict__ cand_p,
                            int* __restrict__ pij, float* __restrict__ out) {
  const int tid = threadIdx.x;
  const int lane = tid & 63, wid = tid >> 6;
  __shared__ float sv[NC];
  __shared__ int sp[NC];
  __shared__ float rv[4];
  __shared__ int rp[4], rq[4];
  __shared__ float selv[20];
  __shared__ int selp[20];

  for (int t = tid; t < NC; t += 256) { sv[t] = cand_v[t]; sp[t] = cand_p[t]; }
  __syncthreads();

  for (int r = 0; r < 20; ++r) {
    float v = -4e30f;
    int p = 0x7fffffff, q = 0;
    for (int t = tid; t < NC; t += 256) {
      float vv = sv[t];
      int pp = sp[t];
      if (better(vv, pp, v, p)) { v = vv; p = pp; q = t; }
    }
    #pragma unroll
    for (int off = 32; off; off >>= 1) {
      float v2 = __shfl_down(v, off);
      int p2 = __shfl_down(p, off);
      int q2 = __shfl_down(q, off);
      if (better(v2, p2, v, p)) { v = v2; p = p2; q = q2; }
    }
    if (lane == 0) { rv[wid] = v; rp[wid] = p; rq[wid] = q; }
    __syncthreads();
    if (tid == 0) {
      #pragma unroll
      for (int t = 1; t < 4; ++t)
        if (better(rv[t], rp[t], v, p)) { v = rv[t]; p = rp[t]; q = rq[t]; }
      selv[r] = v;
      selp[r] = p;
      sv[q] = -3e30f;
    }
    __syncthreads();
  }

  if (tid == 0) {
    int active = 0;
    for (int r = 0; r < 20; ++r) {
      int p = selp[r];
      int i = p >> 8, j = p & 255;
      float s = 1.0f / (1.0f + expf(-selv[r]));
      out[IMP_OFF + r] = s;
      out[PAIR_OFF + 2 * r] = (float)i;
      out[PAIR_OFF + 2 * r + 1] = (float)j;
      if (s > 0.1f) active++;
      pij[r] = i;
      pij[20 + r] = j;
    }
    out[ACT_OFF] = (float)active;
  }
}

// ================= Split path =================
// id_ctx: context MLP + pair-value gather. All inner-loop weight reads are
// ds_read broadcasts (in-order -> precise lgkmcnt pipelining); x + Wc1 chunk
// staged with T14 async-split (global->reg issued one chunk ahead, ds_write
// after barrier). pv/ctx streamed to workspace (coalesced, [k][B] layout).
#define FCH 16
#define NCH (FDIM / FCH)   // 16
#define XSTR 17            // odd stride -> conflict-free column reads

__global__ __launch_bounds__(256, 4) void id_ctx(
    const float* __restrict__ x,
    const float* __restrict__ Wc1, const float* __restrict__ bc1,
    const float* __restrict__ Wc2, const float* __restrict__ bc2,
    const int* __restrict__ pij,
    float* __restrict__ pv_ws, float* __restrict__ ctx_ws,
    float* __restrict__ ctx_sums) {
  __shared__ __align__(16) float xs[256 * XSTR];    // 17408 B
  __shared__ __align__(16) float wc1s[FCH * HH];    // 4096 B
  __shared__ float csum[KK];

  const int tid = threadIdx.x;
  const int b0 = blockIdx.x * 256;
  if (tid < KK) csum[tid] = 0.0f;

  int pcol[2 * KK];
  #pragma unroll
  for (int i = 0; i < 2 * KK; ++i) pcol[i] = __builtin_amdgcn_readfirstlane(pij[i]);

  float h[HH];
  #pragma unroll
  for (int j = 0; j < HH; ++j) h[j] = bc1[j];

  const int srow = tid >> 2;        // 0..63
  const int quad = tid & 3;         // 0..3 (16B each -> 16 floats/row/chunk)
  const float4* __restrict__ Wc1f4 = (const float4*)Wc1;

  float4 xr0, xr1, xr2, xr3, wr;

  // prologue: load + write chunk 0, then issue chunk 1 loads
  {
    const float* xg = x + (size_t)(b0 + srow) * FDIM + quad * 4;
    xr0 = *(const float4*)(xg);
    xr1 = *(const float4*)(xg + (size_t)64 * FDIM);
    xr2 = *(const float4*)(xg + (size_t)128 * FDIM);
    xr3 = *(const float4*)(xg + (size_t)192 * FDIM);
    wr  = Wc1f4[tid];
  }
  {
    float* d0 = &xs[(srow +   0) * XSTR + quad * 4];
    float* d1 = &xs[(srow +  64) * XSTR + quad * 4];
    float* d2 = &xs[(srow + 128) * XSTR + quad * 4];
    float* d3 = &xs[(srow + 192) * XSTR + quad * 4];
    d0[0]=xr0.x; d0[1]=xr0.y; d0[2]=xr0.z; d0[3]=xr0.w;
    d1[0]=xr1.x; d1[1]=xr1.y; d1[2]=xr1.z; d1[3]=xr1.w;
    d2[0]=xr2.x; d2[1]=xr2.y; d2[2]=xr2.z; d2[3]=xr2.w;
    d3[0]=xr3.x; d3[1]=xr3.y; d3[2]=xr3.z; d3[3]=xr3.w;
    *(float4*)&wc1s[tid * 4] = wr;
  }
  {
    const float* xg = x + (size_t)(b0 + srow) * FDIM + FCH + quad * 4;
    xr0 = *(const float4*)(xg);
    xr1 = *(const float4*)(xg + (size_t)64 * FDIM);
    xr2 = *(const float4*)(xg + (size_t)128 * FDIM);
    xr3 = *(const float4*)(xg + (size_t)192 * FDIM);
    wr  = Wc1f4[256 + tid];
  }
  __syncthreads();

  #pragma unroll 1
  for (int c = 0; c < NCH; ++c) {
    const int f0 = c * FCH;
    // pair-value gather for this chunk (uniform branch, coalesced store)
    #pragma unroll
    for (int i = 0; i < 2 * KK; ++i) {
      const int cc = pcol[i];
      if (cc >= f0 && cc < f0 + FCH)
        pv_ws[(size_t)i * BTOT + b0 + tid] = xs[tid * XSTR + (cc - f0)];
    }
    // ctx hidden accumulation over this chunk (all ds_read, broadcast weights)
    #pragma unroll 2
    for (int f = 0; f < FCH; ++f) {
      const float xv = xs[tid * XSTR + f];
      #pragma unroll
      for (int j4 = 0; j4 < HH / 4; ++j4) {
        const float4 w = *(const float4*)&wc1s[f * HH + j4 * 4];
        h[j4*4+0] = fmaf(xv, w.x, h[j4*4+0]);
        h[j4*4+1] = fmaf(xv, w.y, h[j4*4+1]);
        h[j4*4+2] = fmaf(xv, w.z, h[j4*4+2]);
        h[j4*4+3] = fmaf(xv, w.w, h[j4*4+3]);
      }
    }
    __syncthreads();              // all reads of xs/wc1s done
    if (c + 1 < NCH) {
      float* d0 = &xs[(srow +   0) * XSTR + quad * 4];
      float* d1 = &xs[(srow +  64) * XSTR + quad * 4];
      float* d2 = &xs[(srow + 128) * XSTR + quad * 4];
      float* d3 = &xs[(srow + 192) * XSTR + quad * 4];
      d0[0]=xr0.x; d0[1]=xr0.y; d0[2]=xr0.z; d0[3]=xr0.w;
      d1[0]=xr1.x; d1[1]=xr1.y; d1[2]=xr1.z; d1[3]=xr1.w;
      d2[0]=xr2.x; d2[1]=xr2.y; d2[2]=xr2.z; d2[3]=xr2.w;
      d3[0]=xr3.x; d3[1]=xr3.y; d3[2]=xr3.z; d3[3]=xr3.w;
      *(float4*)&wc1s[tid * 4] = wr;
      if (c + 2 < NCH) {
        const int f2 = (c + 2) * FCH;
        const float* xg = x + (size_t)(b0 + srow) * FDIM + f2 + quad * 4;
        xr0 = *(const float4*)(xg);
        xr1 = *(const float4*)(xg + (size_t)64 * FDIM);
        xr2 = *(const float4*)(xg + (size_t)128 * FDIM);
        xr3 = *(const float4*)(xg + (size_t)192 * FDIM);
        wr  = Wc1f4[(size_t)(c + 2) * 256 + tid];
      }
      __syncthreads();            // staged writes visible
    }
  }

  // ---- ctx output layer: fully unrolled, static indices ----
  float ctx[KK];
  #pragma unroll
  for (int k = 0; k < KK; ++k) ctx[k] = bc2[k];
  #pragma unroll
  for (int j = 0; j < HH; ++j) {
    const float hj = fmaxf(h[j], 0.0f);
    const float* __restrict__ wrow = Wc2 + j * KK;
    #pragma unroll
    for (int k = 0; k < KK; ++k) ctx[k] = fmaf(hj, wrow[k], ctx[k]);
  }
  #pragma unroll
  for (int k = 0; k < KK; ++k) {
    ctx[k] = 1.0f / (1.0f + expf(-ctx[k]));
    ctx_ws[(size_t)k * BTOT + b0 + tid] = ctx[k];   // coalesced [k][B]
  }

  // ---- ctx mean: wave shuffle -> LDS -> global atomic ----
  const int lane = tid & 63;
  #pragma unroll
  for (int k = 0; k < KK; ++k) {
    float v = ctx[k];
    #pragma unroll
    for (int off = 32; off; off >>= 1) v += __shfl_down(v, off);
    if (lane == 0) atomicAdd(&csum[k], v);
  }
  __syncthreads();
  if (tid < KK) atomicAdd(&ctx_sums[tid], csum[tid]);
}

// id_pair: the heavy phase (41K FMA/sample). All weights read from LDS
// (broadcast ds_read). W2 double-buffered, one barrier per k, global loads
// for k+2 issued a full iteration ahead (latency fully hidden).
__global__ __launch_bounds__(256, 4) void id_pair(
    const float* __restrict__ W1, const float* __restrict__ b1,
    const float* __restrict__ W2, const float* __restrict__ b2,
    const float* __restrict__ W3, const float* __restrict__ b3,
    const float* __restrict__ pv_ws, const float* __restrict__ ctx_ws,
    float* __restrict__ out) {
  __shared__ __align__(16) float w1s[KK * 2 * HH];    // 10240 B
  __shared__ __align__(16) float b1s[KK * HH];        //  5120 B
  __shared__ __align__(16) float b2s[KK * MM];        //  2560 B
  __shared__ __align__(16) float w3s[KK * MM];        //  2560 B
  __shared__ __align__(16) float b3s[KK];             //    80 B
  __shared__ __align__(16) float w2buf[2][HH * MM];   // 16384 B  (total ~36.2 KB)

  const int tid = threadIdx.x;
  const size_t b = (size_t)blockIdx.x * 256 + tid;
  const float4* __restrict__ W2f4 = (const float4*)W2;

  // stage all small weights once (coalesced global, linear LDS)
  for (int t = tid; t < KK * 2 * HH; t += 256) w1s[t] = W1[t];
  for (int t = tid; t < KK * HH; t += 256)     b1s[t] = b1[t];
  for (int t = tid; t < KK * MM; t += 256)     b2s[t] = b2[t];
  for (int t = tid; t < KK * MM; t += 256)     w3s[t] = W3[t];
  if (tid < KK) b3s[tid] = b3[tid];

  // stage W2[k=0]; prefetch W2[k=1] into regs
  {
    float4 a0 = W2f4[tid];
    float4 a1 = W2f4[256 + tid];
    ((float4*)w2buf[0])[tid] = a0;
    ((float4*)w2buf[0])[256 + tid] = a1;
  }
  float4 r0 = W2f4[512 + tid];
  float4 r1 = W2f4[512 + 256 + tid];
  __syncthreads();

  int cur = 0;
  #pragma unroll 1
  for (int k = 0; k < KK; ++k) {
    // write k+1 into the other buffer (its last readers finished at the
    // end-of-iteration barrier of k-1); issue k+2 loads
    if (k + 1 < KK) {
      ((float4*)w2buf[cur ^ 1])[tid] = r0;
      ((float4*)w2buf[cur ^ 1])[256 + tid] = r1;
      if (k + 2 < KK) {
        r0 = W2f4[(size_t)(k + 2) * 512 + tid];
        r1 = W2f4[(size_t)(k + 2) * 512 + 256 + tid];
      }
    }

    // per-sample inputs (coalesced [k][B] reads, issued early)
    const float pa   = pv_ws[(size_t)k * BTOT + b];
    const float pb   = pv_ws[(size_t)(KK + k) * BTOT + b];
    const float ctxk = ctx_ws[(size_t)k * BTOT + b];

    float h2[MM];
    #pragma unroll
    for (int m4 = 0; m4 < MM / 4; ++m4) {
      const float4 bb = *(const float4*)&b2s[k * MM + m4 * 4];
      h2[m4*4+0]=bb.x; h2[m4*4+1]=bb.y; h2[m4*4+2]=bb.z; h2[m4*4+3]=bb.w;
    }
    const float* __restrict__ w1k = &w1s[k * 2 * HH];
    const float* __restrict__ b1k = &b1s[k * HH];
    const float* __restrict__ w2c = w2buf[cur];

    #pragma unroll 2
    for (int j = 0; j < HH; ++j) {
      const float h1 = fmaxf(fmaf(pa, w1k[j], fmaf(pb, w1k[HH + j], b1k[j])), 0.0f);
      const float* __restrict__ wrow = &w2c[j * MM];
      #pragma unroll
      for (int m4 = 0; m4 < MM / 4; ++m4) {
        const float4 w = *(const float4*)&wrow[m4 * 4];
        h2[m4*4+0] = fmaf(h1, w.x, h2[m4*4+0]);
        h2[m4*4+1] = fmaf(h1, w.y, h2[m4*4+1]);
        h2[m4*4+2] = fmaf(h1, w.z, h2[m4*4+2]);
        h2[m4*4+3] = fmaf(h1, w.w, h2[m4*4+3]);
      }
    }

    float o = b3s[k];
    #pragma unroll
    for (int m = 0; m < MM; ++m) o = fmaf(fmaxf(h2[m], 0.0f), w3s[k * MM + m], o);

    out[b * KK + k] = o * ctxk;   // L2 write-combines the stride-80B stores

    __syncthreads();              // buf[cur] readers done; buf[cur^1] visible
    cur ^= 1;
  }
}

// ================= Fallback fused kernel (round-1, known-passing) =================
#define FCHF 32
#define NCHUNKF (FDIM / FCHF)
#define XSTRF 33

__global__ __launch_bounds__(256, 3) void id_main_fused(
    const float* __restrict__ x,
    const float* __restrict__ Wc1, const float* __restrict__ bc1,
    const float* __restrict__ Wc2, const float* __restrict__ bc2,
    const float* __restrict__ W1, const float* __restrict__ b1,
    const float* __restrict__ W2, const float* __restrict__ b2,
    const float* __restrict__ W3, const float* __restrict__ b3,
    const int* __restrict__ pij,
    float* __restrict__ ctx_sums,
    float* __restrict__ out) {
  __shared__ __align__(16) float xs[256 * XSTRF];
  __shared__ float csum[KK];

  const int tid = threadIdx.x;
  const int b0 = blockIdx.x * 256;
  if (tid < KK) csum[tid] = 0.0f;

  int pcol[2 * KK];
  #pragma unroll
  for (int i = 0; i < 2 * KK; ++i) pcol[i] = __builtin_amdgcn_readfirstlane(pij[i]);

  float h[HH];
  #pragma unroll
  for (int j = 0; j < HH; ++j) h[j] = bc1[j];
  float pv[2 * KK];
  #pragma unroll
  for (int i = 0; i < 2 * KK; ++i) pv[i] = 0.0f;

  const int srow = tid >> 3;
  const int quad = tid & 7;
  const float* __restrict__ xrow_lds = &xs[tid * XSTRF];

  #pragma unroll 1
  for (int c = 0; c < NCHUNKF; ++c) {
    const int f0 = c * FCHF;
    __syncthreads();
    const float* __restrict__ xg = x + (size_t)(b0 + srow) * FDIM + f0 + quad * 4;
    #pragma unroll
    for (int r = 0; r < 8; ++r) {
      const float4 v = *(const float4*)(xg + (size_t)r * 32 * FDIM);
      float* d = &xs[(srow + r * 32) * XSTRF + quad * 4];
      d[0] = v.x; d[1] = v.y; d[2] = v.z; d[3] = v.w;
    }
    __syncthreads();
    #pragma unroll 2
    for (int f = 0; f < FCHF; ++f) {
      const float xv = xrow_lds[f];
      const float* __restrict__ w0 = Wc1 + (size_t)(f0 + f) * HH;
      #pragma unroll
      for (int j = 0; j < HH; ++j) h[j] = fmaf(xv, w0[j], h[j]);
    }
    #pragma unroll
    for (int i = 0; i < 2 * KK; ++i) {
      const int cc = pcol[i];
      if (cc >= f0 && cc < f0 + FCHF) pv[i] = xrow_lds[cc - f0];
    }
  }

  float ctx[KK];
  #pragma unroll
  for (int k = 0; k < KK; ++k) ctx[k] = bc2[k];
  #pragma unroll
  for (int j = 0; j < HH; ++j) {
    const float hj = fmaxf(h[j], 0.0f);
    const float* __restrict__ wr = Wc2 + j * KK;
    #pragma unroll
    for (int k = 0; k < KK; ++k) ctx[k] = fmaf(hj, wr[k], ctx[k]);
  }
  #pragma unroll
  for (int k = 0; k < KK; ++k) ctx[k] = 1.0f / (1.0f + expf(-ctx[k]));

  __syncthreads();
  float* __restrict__ so = xs;

  #pragma unroll 1
  for (int k = 0; k < KK; ++k) {
    float pa = 0.0f, pb = 0.0f;
    #pragma unroll
    for (int i = 0; i < KK; ++i)
      if (k == i) { pa = pv[i]; pb = pv[KK + i]; }

    const float* __restrict__ w1k = W1 + (size_t)k * 2 * HH;
    const float* __restrict__ b1k = b1 + (size_t)k * HH;
    const float* __restrict__ w2k = W2 + (size_t)k * HH * MM;
    const float* __restrict__ b2k = b2 + (size_t)k * MM;

    float h2[MM];
    #pragma unroll
    for (int m = 0; m < MM; ++m) h2[m] = b2k[m];

    #pragma unroll 2
    for (int j = 0; j < HH; ++j) {
      const float h1j = fmaxf(fmaf(pa, w1k[j], fmaf(pb, w1k[HH + j], b1k[j])), 0.0f);
      const float* __restrict__ wr = w2k + j * MM;
      #pragma unroll
      for (int m = 0; m < MM; ++m) h2[m] = fmaf(h1j, wr[m], h2[m]);
    }

    const float* __restrict__ w3k = W3 + (size_t)k * MM;
    float o = b3[k];
    #pragma unroll
    for (int m = 0; m < MM; ++m) o = fmaf(fmaxf(h2[m], 0.0f), w3k[m], o);

    so[tid * KK + k] = o;
  }

  #pragma unroll
  for (int k = 0; k < KK; ++k) so[tid * KK + k] *= ctx[k];

  const int lane = tid & 63;
  #pragma unroll
  for (int k = 0; k < KK; ++k) {
    float v = ctx[k];
    #pragma unroll
    for (int off = 32; off; off >>= 1) v += __shfl_down(v, off);
    if (lane == 0) atomicAdd(&csum[k], v);
  }
  __syncthreads();
  if (tid < KK) atomicAdd(&ctx_sums[tid], csum[tid]);

  const float4* __restrict__ sof = (const float4*)so;
  float4* __restrict__ og = (float4*)(out + (size_t)b0 * KK);
  #pragma unroll
  for (int i = 0; i < 5; ++i) og[tid + i * 256] = sof[tid + i * 256];
}

__global__ void id_finalize(const float* __restrict__ ctx_sums, float* __restrict__ out) {
  const int k = threadIdx.x;
  if (k < KK) out[CWM_OFF + k] = ctx_sums[k] * (1.0f / (float)BTOT);
}

extern "C" void kernel_launch(void* const* d_in, const int* in_sizes, int n_in,
                              void* d_out, int out_size, void* d_ws, size_t ws_size,
                              hipStream_t stream) {
  const float* x   = (const float*)d_in[0];
  const float* iw  = (const float*)d_in[1];
  const float* Wc1 = (const float*)d_in[2];
  const float* bc1 = (const float*)d_in[3];
  const float* Wc2 = (const float*)d_in[4];
  const float* bc2 = (const float*)d_in[5];
  const float* W1  = (const float*)d_in[6];
  const float* b1  = (const float*)d_in[7];
  const float* W2  = (const float*)d_in[8];
  const float* b2  = (const float*)d_in[9];
  const float* W3  = (const float*)d_in[10];
  const float* b3  = (const float*)d_in[11];
  float* out = (float*)d_out;

  float* wsf    = (float*)d_ws;
  float* cand_v = wsf;                  // 5120 floats
  int*   cand_p = (int*)(wsf + 5120);   // 5120 ints
  int*   pij    = (int*)(wsf + 10240);  // 40 ints
  float* csums  = wsf + 10280;          // 20 floats
  float* pv_ws  = wsf + 10304;          // 40*BTOT floats
  float* ctx_ws = wsf + 10304 + (size_t)2 * KK * BTOT;  // 20*BTOT floats
  const size_t need_bytes = ((size_t)10304 + (size_t)3 * KK * BTOT) * sizeof(float); // ~63 MB

  hipMemsetAsync(csums, 0, KK * sizeof(float), stream);
  topk_stage1<<<256, 256, 0, stream>>>(iw, cand_v, cand_p);
  topk_stage2<<<1, 256, 0, stream>>>(cand_v, cand_p, pij, out);
  if (ws_size >= need_bytes) {
    id_ctx<<<BTOT / 256, 256, 0, stream>>>(x, Wc1, bc1, Wc2, bc2, pij,
                                           pv_ws, ctx_ws, csums);
    id_pair<<<BTOT / 256, 256, 0, stream>>>(W1, b1, W2, b2, W3, b3,
                                            pv_ws, ctx_ws, out);
  } else {
    id_main_fused<<<BTOT / 256, 256, 0, stream>>>(x, Wc1, bc1, Wc2, bc2,
                                                  W1, b1, W2, b2, W3, b3,
                                                  pij, csums, out);
  }
  id_finalize<<<1, 64, 0, stream>>>(csums, out);
}